// Round 17
// baseline (520.323 us; speedup 1.0000x reference)
//
#include <hip/hip_runtime.h>
#include <hip/hip_bf16.h>

#define T_SEQ  180
#define LATENT 128
#define HIDDEN 256

typedef __attribute__((ext_vector_type(8))) short  short8;   // 8 x bf16 (4 VGPRs)
typedef __attribute__((ext_vector_type(4))) float  floatx4;  // f32 MFMA acc
typedef __attribute__((ext_vector_type(4))) int    intx4;    // i8 frag / i32 acc

#define LOG2E 1.4426950408889634f

// ---- d_ws layout (BYTES) ----
#define WQ_OFF    0        // w_hh i8 frags: ((wv*6+sub)*4+kc)*1024, 192 KB
#define FCW_OFF   196608   // fc_w bf16 frags (r9/r13 layout), 64 KB
#define SCW_OFF   262144   // w_hh row scales: float[768]
#define OUTW_OFF  265216   // out_w i8 frags: [slice4][lane64][16B] = 4096 B
#define SWOUT_OFF 269312   // out_w row scales: float[2]

// ---- dynamic LDS layout (bytes) ----
// [0,     65536) : n-gate i8 frags: (wv*8 + s2*4 + kc)*1024
// [65536, 74240) : h8 ping-pong: 2 x 16 rows x 272 B
// [74240, 75264) : obuf [pp2][sl4][16][2] float
#define H8A_OFF    65536
#define H8B_OFF    69888
#define OBUF_OFF   74240
#define SMEM_BYTES 75264
#define H8_STRIDE  272

__device__ __forceinline__ unsigned short f2bf(float f) {
    unsigned int u = __float_as_uint(f);
    u += 0x7fffu + ((u >> 16) & 1u);      // round-to-nearest-even
    return (unsigned short)(u >> 16);
}

// exp2-form nonlinearities (log2e pre-folded into the operand by caller)
__device__ __forceinline__ float sig_e2(float ylog2e) {       // sigma(x), y = x*log2e
    return __builtin_amdgcn_rcpf(1.0f + __builtin_amdgcn_exp2f(-ylog2e));
}
__device__ __forceinline__ float tanh_e2(float y2log2e) {     // tanh(x), y = 2x*log2e
    return __builtin_fmaf(-2.0f,
        __builtin_amdgcn_rcpf(1.0f + __builtin_amdgcn_exp2f(y2log2e)), 1.0f);
}

// Per-output-unit scales: one wave per row j of w_hh.
__global__ void pack_scales(const float* __restrict__ whh, float* __restrict__ scales) {
    int wid  = blockIdx.x * 4 + (threadIdx.x >> 6);   // 0..767
    int lane = threadIdx.x & 63;
    const float* src = whh + (size_t)wid * 256 + lane * 4;
    float m = 0.0f;
#pragma unroll
    for (int j = 0; j < 4; ++j) m = fmaxf(m, fabsf(src[j]));
#pragma unroll
    for (int d = 1; d < 64; d <<= 1) m = fmaxf(m, __shfl_xor(m, d, 64));
    if (lane == 0) scales[wid] = m;
}

// Pack w_hh [768,256] fp32 -> i8 16x16x64 B-frags (r13-verified layout).
__global__ void pack_whh_i8(const float* __restrict__ whh, const float* __restrict__ scales,
                            signed char* __restrict__ dst) {
    int tid  = blockIdx.x * blockDim.x + threadIdx.x;  // 12288 threads
    int lane = tid & 63;
    int frag = tid >> 6;                               // 0..191
    int kc   = frag & 3;
    int sub  = (frag >> 2) % 6;
    int w    = frag / 24;
    int g = sub >> 1, cs = sub & 1;
    int col  = w * 32 + cs * 16 + (lane & 15);
    int jout = g * 256 + col;
    int k0   = kc * 64 + ((lane >> 4) << 4);
    const float* src = whh + (size_t)jout * 256 + k0;
    float inv = 127.0f / scales[jout];
    signed char q[16];
#pragma unroll
    for (int j = 0; j < 16; ++j) {
        float v = __builtin_rintf(src[j] * inv);
        v = fminf(fmaxf(v, -127.0f), 127.0f);
        q[j] = (signed char)(int)v;
    }
    *(intx4*)(dst + (size_t)frag * 1024 + lane * 16) = *(intx4*)q;
}

// Pack fc_w [256,128] fp32 -> bf16 16x16x32 B-frags (r9 layout).
__global__ void pack_fcw(const float* __restrict__ fcw, unsigned short* __restrict__ dst) {
    int tid  = blockIdx.x * blockDim.x + threadIdx.x;  // 4096 threads
    int lane = tid & 63;
    int frag = tid >> 6;                               // 0..63
    int kc   = frag & 3;
    int cs   = (frag >> 2) & 1;
    int w    = frag >> 3;
    int col  = w * 32 + cs * 16 + (lane & 15);
    int k0   = kc * 32 + ((lane >> 4) << 3);
    const float* src = fcw + col * 128 + k0;
    unsigned int u[4];
#pragma unroll
    for (int j = 0; j < 4; ++j)
        u[j] = (unsigned int)f2bf(src[2 * j]) | ((unsigned int)f2bf(src[2 * j + 1]) << 16);
    *(uint4*)(dst + frag * 512 + lane * 8) = make_uint4(u[0], u[1], u[2], u[3]);
}

// Quantize out_w [2,256] -> i8 proj B-frags [slice4][lane][16B] + row scales.
__global__ void pack_outw_i8(const float* __restrict__ out_w,
                             signed char* __restrict__ dst, float* __restrict__ swout) {
    __shared__ float sw[2];
    int tid = threadIdx.x;
    if (tid < 128) {
        int o = tid >> 6, lane = tid & 63;
        const float* src = out_w + o * 256 + lane * 4;
        float m = 0.0f;
#pragma unroll
        for (int j = 0; j < 4; ++j) m = fmaxf(m, fabsf(src[j]));
#pragma unroll
        for (int d = 1; d < 64; d <<= 1) m = fmaxf(m, __shfl_xor(m, d, 64));
        if (lane == 0) { sw[o] = m; swout[o] = m; }
    }
    __syncthreads();
    int sl = tid >> 6, lane = tid & 63;
    int n  = lane & 15;
    int k0 = sl * 64 + ((lane >> 4) << 4);
    signed char q[16];
#pragma unroll
    for (int j = 0; j < 16; ++j) {
        float v = 0.0f;
        if (n < 2) {
            v = __builtin_rintf(out_w[n * 256 + k0 + j] * (127.0f / sw[n]));
            v = fminf(fmaxf(v, -127.0f), 127.0f);
        }
        q[j] = (signed char)(int)v;
    }
    *(intx4*)(dst + sl * 1024 + lane * 16) = *(intx4*)q;
}

// Persistent GRU r17 = r16 + waves_per_eu(4,4) register pin. r16's allocator
// targeted 8 waves/EU (VGPR=64) and spilled wq to scratch (WRITE_SIZE 65 MB),
// even though LDS (75 KB/block) caps the CU at 2 blocks = 4 waves/SIMD anyway.
// max=4 makes the 8-wave target illegal -> full 128-reg budget, wq in regs.
// 512 blocks x 512 thr, 16 rows/block, 2 blocks/CU: independent per-block
// barriers interleave the two blocks' MFMA and VALU phases (m114 via
// occupancy -- intra-block overlap falsified r7-r10). i8 everywhere (r14);
// exp2-form gates with log2e folded into scales.
__global__ void __launch_bounds__(512)
__attribute__((amdgpu_waves_per_eu(4, 4)))
gru_main(
    const float* __restrict__ z,
    const float* __restrict__ fc_b,
    const float* __restrict__ b_ih,
    const float* __restrict__ b_hh,
    const float* __restrict__ out_b,
    const unsigned char* __restrict__ ws,
    float* __restrict__ out)
{
    extern __shared__ unsigned char smem[];
    signed char* wlds = (signed char*)smem;                 // n-gate frags
    signed char* h8a  = (signed char*)(smem + H8A_OFF);
    signed char* h8b  = (signed char*)(smem + H8B_OFF);
    float*       obuf = (float*)(smem + OBUF_OFF);          // [2][4][16][2]

    const int tid  = threadIdx.x;
    const int lane = tid & 63;
    const int wv   = tid >> 6;
    const int l15  = lane & 15;
    const int qd   = lane >> 4;
    const int rb   = blockIdx.x * 16;

    // ---- stage n-gate i8 frags into LDS (8 KB per wave) ----
#pragma unroll
    for (int s2 = 0; s2 < 2; ++s2)
#pragma unroll
        for (int kc = 0; kc < 4; ++kc) {
            int gfrag = (wv * 6 + 4 + s2) * 4 + kc;
            intx4 v = *(const intx4*)(ws + WQ_OFF + (size_t)gfrag * 1024 + lane * 16);
            *(intx4*)(wlds + (wv * 8 + s2 * 4 + kc) * 1024 + lane * 16) = v;
        }

    // ---- r,z-gate i8 frags into registers (16 frags = 64 VGPRs) ----
    intx4 wq[16];
#pragma unroll
    for (int sub = 0; sub < 4; ++sub)
#pragma unroll
        for (int kc = 0; kc < 4; ++kc)
            wq[sub * 4 + kc] = *(const intx4*)(ws + WQ_OFF
                                + (size_t)((wv * 6 + sub) * 4 + kc) * 1024 + lane * 16);

    // ---- proj B-frag (i8, waves 0-3 only) + per-lane constants ----
    intx4 bproj = *(const intx4*)(ws + OUTW_OFF + (wv & 3) * 1024 + lane * 16);
    const float* swout = (const float*)(ws + SWOUT_OFF);
    float psc = (l15 < 2) ? swout[l15] * (1.0f / 16129.0f) : 0.0f;

    const float* scales = (const float*)(ws + SCW_OFF);
    float cbrE[2], cbzE[2], bhnE2[2], binE2[2], fcbE2[2];
    float scqrE[2], scqzE[2], scqnE2[2];
#pragma unroll
    for (int cs = 0; cs < 2; ++cs) {
        int col = wv * 32 + cs * 16 + l15;
        cbrE[cs]  = (b_ih[col]       + b_hh[col])       * LOG2E;
        cbzE[cs]  = (b_ih[256 + col] + b_hh[256 + col]) * LOG2E;
        binE2[cs] = b_ih[512 + col] * (2.0f * LOG2E);
        bhnE2[cs] = b_hh[512 + col] * (2.0f * LOG2E);
        fcbE2[cs] = fc_b[col] * (2.0f * LOG2E);
        float s0 = scales[col]       * (1.0f / 16129.0f);
        float s1 = scales[256 + col] * (1.0f / 16129.0f);
        float s2 = scales[512 + col] * (1.0f / 16129.0f);
        scqrE[cs]  = s0 * LOG2E;
        scqzE[cs]  = s1 * LOG2E;
        scqnE2[cs] = s2 * (2.0f * LOG2E);
    }
    // every thread loads the correct output bias (r15 bug fixed in r16)
    float ob = out_b[tid & 1];

    // ---- h0 = tanh(z @ fc_w^T + fc_b): bf16 MFMA, A-frags direct from global ----
    floatx4 a0f[2];
#pragma unroll
    for (int cs = 0; cs < 2; ++cs) a0f[cs] = (floatx4){0.f, 0.f, 0.f, 0.f};
#pragma unroll
    for (int kc = 0; kc < 4; ++kc) {
        const float* zp = z + (size_t)(rb + l15) * LATENT + kc * 32 + qd * 8;
        short8 afr;
#pragma unroll
        for (int j = 0; j < 8; ++j) afr[j] = (short)f2bf(zp[j]);
#pragma unroll
        for (int cs = 0; cs < 2; ++cs) {
            short8 bfr = *(const short8*)(ws + FCW_OFF
                            + (size_t)((wv * 2 + cs) * 4 + kc) * 1024 + lane * 16);
            a0f[cs] = __builtin_amdgcn_mfma_f32_16x16x32_bf16(afr, bfr, a0f[cs], 0, 0, 0);
        }
    }

    float hm[2][4];
#pragma unroll
    for (int cs = 0; cs < 2; ++cs)
#pragma unroll
        for (int r = 0; r < 4; ++r) {
            float h = tanh_e2(__builtin_fmaf(a0f[cs][r], 2.0f * LOG2E, fcbE2[cs]));
            hm[cs][r] = h;
            h8a[(qd * 4 + r) * H8_STRIDE + wv * 32 + cs * 16 + l15] =
                (signed char)(int)__builtin_rintf(h * 127.0f);
        }
    __syncthreads();

    // ---- 180 monolithic steps, ONE barrier each ----
#pragma unroll 1
    for (int t = 0; t < T_SEQ; ++t) {
        const int p = t & 1;
        signed char* h8p = p ? h8b : h8a;       // read: state s_t
        signed char* h8n = p ? h8a : h8b;       // write: state s_{t+1}

        // gate MFMAs: 24 i8 (6 acc x 4 kc); r,z B from regs, n B from LDS
        intx4 acc[6];
#pragma unroll
        for (int s = 0; s < 6; ++s) acc[s] = (intx4){0, 0, 0, 0};
#pragma unroll
        for (int kc = 0; kc < 4; ++kc) {
            intx4 a8 = *(const intx4*)&h8p[l15 * H8_STRIDE + kc * 64 + qd * 16];
#pragma unroll
            for (int s = 0; s < 4; ++s)
                acc[s] = __builtin_amdgcn_mfma_i32_16x16x64_i8(a8, wq[s * 4 + kc], acc[s], 0, 0, 0);
            intx4 bn0 = *(const intx4*)(wlds + (wv * 8 + 0 + kc) * 1024 + lane * 16);
            intx4 bn1 = *(const intx4*)(wlds + (wv * 8 + 4 + kc) * 1024 + lane * 16);
            acc[4] = __builtin_amdgcn_mfma_i32_16x16x64_i8(a8, bn0, acc[4], 0, 0, 0);
            acc[5] = __builtin_amdgcn_mfma_i32_16x16x64_i8(a8, bn1, acc[5], 0, 0, 0);
        }

        // proj of s_t (out idx t-1): waves 0-3, 64-col k-slice each
        intx4 pj = (intx4){0, 0, 0, 0};
        if (wv < 4) {
            intx4 a8p = *(const intx4*)&h8p[l15 * H8_STRIDE + (wv & 3) * 64 + qd * 16];
            pj = __builtin_amdgcn_mfma_i32_16x16x64_i8(a8p, bproj, pj, 0, 0, 0);
        }

        // flush obuf written at step t-1 (out idx t-2); wave 4 owns this
        if (t >= 2 && tid >= 256 && tid < 288) {
            int rl = (tid - 256) >> 1, o = tid & 1;
            int base = (p ^ 1) * 128 + rl * 2 + o;
            float s = ob + obuf[base] + obuf[base + 32] + obuf[base + 64] + obuf[base + 96];
            out[(size_t)(rb + rl) * (T_SEQ * 2) + (t - 2) * 2 + o] = s;
        }

        // gates -> s_{t+1} (exp2-form, log2e pre-folded), write h8 next buffer
#pragma unroll
        for (int cs = 0; cs < 2; ++cs)
#pragma unroll
            for (int r = 0; r < 4; ++r) {
                float yr  = __builtin_fmaf((float)acc[cs][r],     scqrE[cs],  cbrE[cs]);
                float yz  = __builtin_fmaf((float)acc[2 + cs][r], scqzE[cs],  cbzE[cs]);
                float xn2 = __builtin_fmaf((float)acc[4 + cs][r], scqnE2[cs], bhnE2[cs]);
                float gr = sig_e2(yr);
                float gz = sig_e2(yz);
                float gn = tanh_e2(__builtin_fmaf(gr, xn2, binE2[cs]));
                float h  = __builtin_fmaf(gz, hm[cs][r] - gn, gn);
                hm[cs][r] = h;
                h8n[(qd * 4 + r) * H8_STRIDE + wv * 32 + cs * 16 + l15] =
                    (signed char)(int)__builtin_rintf(h * 127.0f);
            }

        // stash proj partials (out idx t-1) into obuf[p]
        if (t >= 1 && wv < 4 && l15 < 2) {
#pragma unroll
            for (int r = 0; r < 4; ++r)
                obuf[p * 128 + (wv & 3) * 32 + (qd * 4 + r) * 2 + l15] = (float)pj[r] * psc;
        }

        __syncthreads();   // the single per-step barrier
    }

    // ---- epilogue ----
    if (tid < 32) {        // flush obuf[1] (stashed at t=179): out idx 178
        int rl = tid >> 1, o = tid & 1;
        int base = 128 + rl * 2 + o;
        float s = ob + obuf[base] + obuf[base + 32] + obuf[base + 64] + obuf[base + 96];
        out[(size_t)(rb + rl) * (T_SEQ * 2) + 178 * 2 + o] = s;
    }
    if (wv < 4) {          // proj of s_180 (in h8a after step 179) -> obuf[0]
        intx4 a8p = *(const intx4*)&h8a[l15 * H8_STRIDE + (wv & 3) * 64 + qd * 16];
        intx4 pj = (intx4){0, 0, 0, 0};
        pj = __builtin_amdgcn_mfma_i32_16x16x64_i8(a8p, bproj, pj, 0, 0, 0);
        if (l15 < 2)
#pragma unroll
            for (int r = 0; r < 4; ++r)
                obuf[(wv & 3) * 32 + (qd * 4 + r) * 2 + l15] = (float)pj[r] * psc;
    }
    __syncthreads();
    if (tid < 32) {        // flush obuf[0]: out idx 179
        int rl = tid >> 1, o = tid & 1;
        int base = rl * 2 + o;
        float s = ob + obuf[base] + obuf[base + 32] + obuf[base + 64] + obuf[base + 96];
        out[(size_t)(rb + rl) * (T_SEQ * 2) + 179 * 2 + o] = s;
    }
}

extern "C" void kernel_launch(void* const* d_in, const int* in_sizes, int n_in,
                              void* d_out, int out_size, void* d_ws, size_t ws_size,
                              hipStream_t stream) {
    const float* z     = (const float*)d_in[0];
    const float* fc_w  = (const float*)d_in[1];
    const float* fc_b  = (const float*)d_in[2];
    // d_in[3] = w_ih : unused (GRU input is all-zeros, gi = b_ih)
    const float* b_ih  = (const float*)d_in[4];
    const float* w_hh  = (const float*)d_in[5];
    const float* b_hh  = (const float*)d_in[6];
    const float* out_w = (const float*)d_in[7];
    const float* out_b = (const float*)d_in[8];
    float* out = (float*)d_out;
    unsigned char* ws = (unsigned char*)d_ws;   // needs 269,320 B

    hipFuncSetAttribute((const void*)gru_main,
                        hipFuncAttributeMaxDynamicSharedMemorySize, SMEM_BYTES);

    pack_scales<<<192, 256, 0, stream>>>(w_hh, (float*)(ws + SCW_OFF));
    pack_whh_i8<<<48, 256, 0, stream>>>(w_hh, (const float*)(ws + SCW_OFF),
                                        (signed char*)(ws + WQ_OFF));
    pack_fcw<<<16, 256, 0, stream>>>(fc_w, (unsigned short*)(ws + FCW_OFF));
    pack_outw_i8<<<1, 256, 0, stream>>>(out_w, (signed char*)(ws + OUTW_OFF),
                                        (float*)(ws + SWOUT_OFF));
    gru_main<<<512, 512, SMEM_BYTES, stream>>>(z, fc_b, b_ih, b_hh, out_b, ws, out);
}

// Round 18
// 517.761 us; speedup vs baseline: 1.0049x; 1.0049x over previous
//
#include <hip/hip_runtime.h>
#include <hip/hip_bf16.h>

#define T_SEQ  180
#define LATENT 128
#define HIDDEN 256

typedef __attribute__((ext_vector_type(8))) short  short8;   // 8 x bf16 (4 VGPRs)
typedef __attribute__((ext_vector_type(4))) float  floatx4;  // f32 MFMA acc
typedef __attribute__((ext_vector_type(4))) int    intx4;    // i8 frag / i32 acc

#define LOG2E 1.4426950408889634f

// ---- d_ws layout (BYTES) ----
#define WQ_OFF    0        // w_hh i8 frags: ((wv*6+sub)*4+kc)*1024, 192 KB
#define FCW_OFF   196608   // fc_w bf16 frags (r9/r13 layout), 64 KB
#define SCW_OFF   262144   // w_hh row scales: float[768]
#define OUTW_OFF  265216   // out_w i8 frags: [slice4][lane64][16B] = 4096 B
#define SWOUT_OFF 269312   // out_w row scales: float[2]

// ---- dynamic LDS layout (bytes) ----
// [0,     65536) : n-gate i8 frags: (wv*8 + s2*4 + kc)*1024
// [65536, 74240) : h8 ping-pong: 2 x 16 rows x 272 B
// [74240, 75264) : obuf [pp2][sl4][16][2] float
#define H8A_OFF    65536
#define H8B_OFF    69888
#define OBUF_OFF   74240
#define SMEM_BYTES 75264
#define H8_STRIDE  272

__device__ __forceinline__ unsigned short f2bf(float f) {
    unsigned int u = __float_as_uint(f);
    u += 0x7fffu + ((u >> 16) & 1u);      // round-to-nearest-even
    return (unsigned short)(u >> 16);
}

// exp2-form nonlinearities (log2e pre-folded into the operand by caller)
__device__ __forceinline__ float sig_e2(float ylog2e) {       // sigma(x), y = x*log2e
    return __builtin_amdgcn_rcpf(1.0f + __builtin_amdgcn_exp2f(-ylog2e));
}
__device__ __forceinline__ float tanh_e2(float y2log2e) {     // tanh(x), y = 2x*log2e
    return __builtin_fmaf(-2.0f,
        __builtin_amdgcn_rcpf(1.0f + __builtin_amdgcn_exp2f(y2log2e)), 1.0f);
}

// Per-output-unit scales: one wave per row j of w_hh.
__global__ void pack_scales(const float* __restrict__ whh, float* __restrict__ scales) {
    int wid  = blockIdx.x * 4 + (threadIdx.x >> 6);   // 0..767
    int lane = threadIdx.x & 63;
    const float* src = whh + (size_t)wid * 256 + lane * 4;
    float m = 0.0f;
#pragma unroll
    for (int j = 0; j < 4; ++j) m = fmaxf(m, fabsf(src[j]));
#pragma unroll
    for (int d = 1; d < 64; d <<= 1) m = fmaxf(m, __shfl_xor(m, d, 64));
    if (lane == 0) scales[wid] = m;
}

// Pack w_hh [768,256] fp32 -> i8 16x16x64 B-frags (r13-verified layout).
__global__ void pack_whh_i8(const float* __restrict__ whh, const float* __restrict__ scales,
                            signed char* __restrict__ dst) {
    int tid  = blockIdx.x * blockDim.x + threadIdx.x;  // 12288 threads
    int lane = tid & 63;
    int frag = tid >> 6;                               // 0..191
    int kc   = frag & 3;
    int sub  = (frag >> 2) % 6;
    int w    = frag / 24;
    int g = sub >> 1, cs = sub & 1;
    int col  = w * 32 + cs * 16 + (lane & 15);
    int jout = g * 256 + col;
    int k0   = kc * 64 + ((lane >> 4) << 4);
    const float* src = whh + (size_t)jout * 256 + k0;
    float inv = 127.0f / scales[jout];
    signed char q[16];
#pragma unroll
    for (int j = 0; j < 16; ++j) {
        float v = __builtin_rintf(src[j] * inv);
        v = fminf(fmaxf(v, -127.0f), 127.0f);
        q[j] = (signed char)(int)v;
    }
    *(intx4*)(dst + (size_t)frag * 1024 + lane * 16) = *(intx4*)q;
}

// Pack fc_w [256,128] fp32 -> bf16 16x16x32 B-frags (r9 layout).
__global__ void pack_fcw(const float* __restrict__ fcw, unsigned short* __restrict__ dst) {
    int tid  = blockIdx.x * blockDim.x + threadIdx.x;  // 4096 threads
    int lane = tid & 63;
    int frag = tid >> 6;                               // 0..63
    int kc   = frag & 3;
    int cs   = (frag >> 2) & 1;
    int w    = frag >> 3;
    int col  = w * 32 + cs * 16 + (lane & 15);
    int k0   = kc * 32 + ((lane >> 4) << 3);
    const float* src = fcw + col * 128 + k0;
    unsigned int u[4];
#pragma unroll
    for (int j = 0; j < 4; ++j)
        u[j] = (unsigned int)f2bf(src[2 * j]) | ((unsigned int)f2bf(src[2 * j + 1]) << 16);
    *(uint4*)(dst + frag * 512 + lane * 8) = make_uint4(u[0], u[1], u[2], u[3]);
}

// Quantize out_w [2,256] -> i8 proj B-frags [slice4][lane][16B] + row scales.
__global__ void pack_outw_i8(const float* __restrict__ out_w,
                             signed char* __restrict__ dst, float* __restrict__ swout) {
    __shared__ float sw[2];
    int tid = threadIdx.x;
    if (tid < 128) {
        int o = tid >> 6, lane = tid & 63;
        const float* src = out_w + o * 256 + lane * 4;
        float m = 0.0f;
#pragma unroll
        for (int j = 0; j < 4; ++j) m = fmaxf(m, fabsf(src[j]));
#pragma unroll
        for (int d = 1; d < 64; d <<= 1) m = fmaxf(m, __shfl_xor(m, d, 64));
        if (lane == 0) { sw[o] = m; swout[o] = m; }
    }
    __syncthreads();
    int sl = tid >> 6, lane = tid & 63;
    int n  = lane & 15;
    int k0 = sl * 64 + ((lane >> 4) << 4);
    signed char q[16];
#pragma unroll
    for (int j = 0; j < 16; ++j) {
        float v = 0.0f;
        if (n < 2) {
            v = __builtin_rintf(out_w[n * 256 + k0 + j] * (127.0f / sw[n]));
            v = fminf(fmaxf(v, -127.0f), 127.0f);
        }
        q[j] = (signed char)(int)v;
    }
    *(intx4*)(dst + sl * 1024 + lane * 16) = *(intx4*)q;
}

// Persistent GRU r18 = r16 structure + __launch_bounds__(512, 2) register fix.
// r16/(512,4) and r17/waves_per_eu(4,4) both left the allocator at 64 VGPR
// with ~50 MB scratch spill of wq; r14 proved (512,2) yields ~120 VGPR with
// zero spill. Actual residency stays 2 blocks/CU (LDS 75 KB/block caps it;
// 121 regs <= 128 permits 4 waves/SIMD). 512 blocks x 512 thr, 16 rows/block:
// independent per-block barriers interleave the two blocks' MFMA and VALU
// phases (m114 via occupancy -- intra-block overlap falsified r7-r10).
// i8 everywhere (r14); exp2-form gates with log2e folded into scales.
__global__ __launch_bounds__(512, 2) void gru_main(
    const float* __restrict__ z,
    const float* __restrict__ fc_b,
    const float* __restrict__ b_ih,
    const float* __restrict__ b_hh,
    const float* __restrict__ out_b,
    const unsigned char* __restrict__ ws,
    float* __restrict__ out)
{
    extern __shared__ unsigned char smem[];
    signed char* wlds = (signed char*)smem;                 // n-gate frags
    signed char* h8a  = (signed char*)(smem + H8A_OFF);
    signed char* h8b  = (signed char*)(smem + H8B_OFF);
    float*       obuf = (float*)(smem + OBUF_OFF);          // [2][4][16][2]

    const int tid  = threadIdx.x;
    const int lane = tid & 63;
    const int wv   = tid >> 6;
    const int l15  = lane & 15;
    const int qd   = lane >> 4;
    const int rb   = blockIdx.x * 16;

    // ---- stage n-gate i8 frags into LDS (8 KB per wave) ----
#pragma unroll
    for (int s2 = 0; s2 < 2; ++s2)
#pragma unroll
        for (int kc = 0; kc < 4; ++kc) {
            int gfrag = (wv * 6 + 4 + s2) * 4 + kc;
            intx4 v = *(const intx4*)(ws + WQ_OFF + (size_t)gfrag * 1024 + lane * 16);
            *(intx4*)(wlds + (wv * 8 + s2 * 4 + kc) * 1024 + lane * 16) = v;
        }

    // ---- r,z-gate i8 frags into registers (16 frags = 64 VGPRs) ----
    intx4 wq[16];
#pragma unroll
    for (int sub = 0; sub < 4; ++sub)
#pragma unroll
        for (int kc = 0; kc < 4; ++kc)
            wq[sub * 4 + kc] = *(const intx4*)(ws + WQ_OFF
                                + (size_t)((wv * 6 + sub) * 4 + kc) * 1024 + lane * 16);

    // ---- proj B-frag (i8, waves 0-3 only) + per-lane constants ----
    intx4 bproj = *(const intx4*)(ws + OUTW_OFF + (wv & 3) * 1024 + lane * 16);
    const float* swout = (const float*)(ws + SWOUT_OFF);
    float psc = (l15 < 2) ? swout[l15] * (1.0f / 16129.0f) : 0.0f;

    const float* scales = (const float*)(ws + SCW_OFF);
    float cbrE[2], cbzE[2], bhnE2[2], binE2[2], fcbE2[2];
    float scqrE[2], scqzE[2], scqnE2[2];
#pragma unroll
    for (int cs = 0; cs < 2; ++cs) {
        int col = wv * 32 + cs * 16 + l15;
        cbrE[cs]  = (b_ih[col]       + b_hh[col])       * LOG2E;
        cbzE[cs]  = (b_ih[256 + col] + b_hh[256 + col]) * LOG2E;
        binE2[cs] = b_ih[512 + col] * (2.0f * LOG2E);
        bhnE2[cs] = b_hh[512 + col] * (2.0f * LOG2E);
        fcbE2[cs] = fc_b[col] * (2.0f * LOG2E);
        float s0 = scales[col]       * (1.0f / 16129.0f);
        float s1 = scales[256 + col] * (1.0f / 16129.0f);
        float s2 = scales[512 + col] * (1.0f / 16129.0f);
        scqrE[cs]  = s0 * LOG2E;
        scqzE[cs]  = s1 * LOG2E;
        scqnE2[cs] = s2 * (2.0f * LOG2E);
    }
    // every thread loads the correct output bias (r15 bug fixed in r16)
    float ob = out_b[tid & 1];

    // ---- h0 = tanh(z @ fc_w^T + fc_b): bf16 MFMA, A-frags direct from global ----
    floatx4 a0f[2];
#pragma unroll
    for (int cs = 0; cs < 2; ++cs) a0f[cs] = (floatx4){0.f, 0.f, 0.f, 0.f};
#pragma unroll
    for (int kc = 0; kc < 4; ++kc) {
        const float* zp = z + (size_t)(rb + l15) * LATENT + kc * 32 + qd * 8;
        short8 afr;
#pragma unroll
        for (int j = 0; j < 8; ++j) afr[j] = (short)f2bf(zp[j]);
#pragma unroll
        for (int cs = 0; cs < 2; ++cs) {
            short8 bfr = *(const short8*)(ws + FCW_OFF
                            + (size_t)((wv * 2 + cs) * 4 + kc) * 1024 + lane * 16);
            a0f[cs] = __builtin_amdgcn_mfma_f32_16x16x32_bf16(afr, bfr, a0f[cs], 0, 0, 0);
        }
    }

    float hm[2][4];
#pragma unroll
    for (int cs = 0; cs < 2; ++cs)
#pragma unroll
        for (int r = 0; r < 4; ++r) {
            float h = tanh_e2(__builtin_fmaf(a0f[cs][r], 2.0f * LOG2E, fcbE2[cs]));
            hm[cs][r] = h;
            h8a[(qd * 4 + r) * H8_STRIDE + wv * 32 + cs * 16 + l15] =
                (signed char)(int)__builtin_rintf(h * 127.0f);
        }
    __syncthreads();

    // ---- 180 monolithic steps, ONE barrier each ----
#pragma unroll 1
    for (int t = 0; t < T_SEQ; ++t) {
        const int p = t & 1;
        signed char* h8p = p ? h8b : h8a;       // read: state s_t
        signed char* h8n = p ? h8a : h8b;       // write: state s_{t+1}

        // gate MFMAs: 24 i8 (6 acc x 4 kc); r,z B from regs, n B from LDS
        intx4 acc[6];
#pragma unroll
        for (int s = 0; s < 6; ++s) acc[s] = (intx4){0, 0, 0, 0};
#pragma unroll
        for (int kc = 0; kc < 4; ++kc) {
            intx4 a8 = *(const intx4*)&h8p[l15 * H8_STRIDE + kc * 64 + qd * 16];
#pragma unroll
            for (int s = 0; s < 4; ++s)
                acc[s] = __builtin_amdgcn_mfma_i32_16x16x64_i8(a8, wq[s * 4 + kc], acc[s], 0, 0, 0);
            intx4 bn0 = *(const intx4*)(wlds + (wv * 8 + 0 + kc) * 1024 + lane * 16);
            intx4 bn1 = *(const intx4*)(wlds + (wv * 8 + 4 + kc) * 1024 + lane * 16);
            acc[4] = __builtin_amdgcn_mfma_i32_16x16x64_i8(a8, bn0, acc[4], 0, 0, 0);
            acc[5] = __builtin_amdgcn_mfma_i32_16x16x64_i8(a8, bn1, acc[5], 0, 0, 0);
        }

        // proj of s_t (out idx t-1): waves 0-3, 64-col k-slice each
        intx4 pj = (intx4){0, 0, 0, 0};
        if (wv < 4) {
            intx4 a8p = *(const intx4*)&h8p[l15 * H8_STRIDE + (wv & 3) * 64 + qd * 16];
            pj = __builtin_amdgcn_mfma_i32_16x16x64_i8(a8p, bproj, pj, 0, 0, 0);
        }

        // flush obuf written at step t-1 (out idx t-2); wave 4 owns this
        if (t >= 2 && tid >= 256 && tid < 288) {
            int rl = (tid - 256) >> 1, o = tid & 1;
            int base = (p ^ 1) * 128 + rl * 2 + o;
            float s = ob + obuf[base] + obuf[base + 32] + obuf[base + 64] + obuf[base + 96];
            out[(size_t)(rb + rl) * (T_SEQ * 2) + (t - 2) * 2 + o] = s;
        }

        // gates -> s_{t+1} (exp2-form, log2e pre-folded), write h8 next buffer
#pragma unroll
        for (int cs = 0; cs < 2; ++cs)
#pragma unroll
            for (int r = 0; r < 4; ++r) {
                float yr  = __builtin_fmaf((float)acc[cs][r],     scqrE[cs],  cbrE[cs]);
                float yz  = __builtin_fmaf((float)acc[2 + cs][r], scqzE[cs],  cbzE[cs]);
                float xn2 = __builtin_fmaf((float)acc[4 + cs][r], scqnE2[cs], bhnE2[cs]);
                float gr = sig_e2(yr);
                float gz = sig_e2(yz);
                float gn = tanh_e2(__builtin_fmaf(gr, xn2, binE2[cs]));
                float h  = __builtin_fmaf(gz, hm[cs][r] - gn, gn);
                hm[cs][r] = h;
                h8n[(qd * 4 + r) * H8_STRIDE + wv * 32 + cs * 16 + l15] =
                    (signed char)(int)__builtin_rintf(h * 127.0f);
            }

        // stash proj partials (out idx t-1) into obuf[p]
        if (t >= 1 && wv < 4 && l15 < 2) {
#pragma unroll
            for (int r = 0; r < 4; ++r)
                obuf[p * 128 + (wv & 3) * 32 + (qd * 4 + r) * 2 + l15] = (float)pj[r] * psc;
        }

        __syncthreads();   // the single per-step barrier
    }

    // ---- epilogue ----
    if (tid < 32) {        // flush obuf[1] (stashed at t=179): out idx 178
        int rl = tid >> 1, o = tid & 1;
        int base = 128 + rl * 2 + o;
        float s = ob + obuf[base] + obuf[base + 32] + obuf[base + 64] + obuf[base + 96];
        out[(size_t)(rb + rl) * (T_SEQ * 2) + 178 * 2 + o] = s;
    }
    if (wv < 4) {          // proj of s_180 (in h8a after step 179) -> obuf[0]
        intx4 a8p = *(const intx4*)&h8a[l15 * H8_STRIDE + (wv & 3) * 64 + qd * 16];
        intx4 pj = (intx4){0, 0, 0, 0};
        pj = __builtin_amdgcn_mfma_i32_16x16x64_i8(a8p, bproj, pj, 0, 0, 0);
        if (l15 < 2)
#pragma unroll
            for (int r = 0; r < 4; ++r)
                obuf[(wv & 3) * 32 + (qd * 4 + r) * 2 + l15] = (float)pj[r] * psc;
    }
    __syncthreads();
    if (tid < 32) {        // flush obuf[0]: out idx 179
        int rl = tid >> 1, o = tid & 1;
        int base = rl * 2 + o;
        float s = ob + obuf[base] + obuf[base + 32] + obuf[base + 64] + obuf[base + 96];
        out[(size_t)(rb + rl) * (T_SEQ * 2) + 179 * 2 + o] = s;
    }
}

extern "C" void kernel_launch(void* const* d_in, const int* in_sizes, int n_in,
                              void* d_out, int out_size, void* d_ws, size_t ws_size,
                              hipStream_t stream) {
    const float* z     = (const float*)d_in[0];
    const float* fc_w  = (const float*)d_in[1];
    const float* fc_b  = (const float*)d_in[2];
    // d_in[3] = w_ih : unused (GRU input is all-zeros, gi = b_ih)
    const float* b_ih  = (const float*)d_in[4];
    const float* w_hh  = (const float*)d_in[5];
    const float* b_hh  = (const float*)d_in[6];
    const float* out_w = (const float*)d_in[7];
    const float* out_b = (const float*)d_in[8];
    float* out = (float*)d_out;
    unsigned char* ws = (unsigned char*)d_ws;   // needs 269,320 B

    hipFuncSetAttribute((const void*)gru_main,
                        hipFuncAttributeMaxDynamicSharedMemorySize, SMEM_BYTES);

    pack_scales<<<192, 256, 0, stream>>>(w_hh, (float*)(ws + SCW_OFF));
    pack_whh_i8<<<48, 256, 0, stream>>>(w_hh, (const float*)(ws + SCW_OFF),
                                        (signed char*)(ws + WQ_OFF));
    pack_fcw<<<16, 256, 0, stream>>>(fc_w, (unsigned short*)(ws + FCW_OFF));
    pack_outw_i8<<<1, 256, 0, stream>>>(out_w, (signed char*)(ws + OUTW_OFF),
                                        (float*)(ws + SWOUT_OFF));
    gru_main<<<512, 512, SMEM_BYTES, stream>>>(z, fc_b, b_ih, b_hh, out_b, ws, out);
}

// Round 19
// 480.104 us; speedup vs baseline: 1.0838x; 1.0784x over previous
//
#include <hip/hip_runtime.h>
#include <hip/hip_bf16.h>

#define T_SEQ  180
#define LATENT 128
#define HIDDEN 256

typedef __attribute__((ext_vector_type(8))) short  short8;   // 8 x bf16 (4 VGPRs)
typedef __attribute__((ext_vector_type(4))) float  floatx4;  // f32 MFMA acc
typedef __attribute__((ext_vector_type(4))) int    intx4;    // i8 frag / i32 acc

#define LOG2E 1.4426950408889634f

// ---- d_ws layout (BYTES) ----
#define WQ_OFF    0        // w_hh i8 frags: ((w*6+sub)*4+kc)*1024, 192 KB
#define FCW_OFF   196608   // fc_w bf16 frags (r9/r13 layout), 64 KB
#define SCW_OFF   262144   // w_hh row scales: float[768]
#define OUTW_OFF  265216   // out_w i8 frags: [slice4][lane64][16B] = 4096 B
#define SWOUT_OFF 269312   // out_w row scales: float[2]

// ---- dynamic LDS layout (bytes) ----
// h8 ping-pong: 2 x 32 rows x 272 B; obuf [pp2][rh2][sl4][16][2] floats
#define H8_STRIDE  272
#define H8B_OFF    8704
#define OBUF_OFF   17408
#define SMEM_BYTES 19456

__device__ __forceinline__ unsigned short f2bf(float f) {
    unsigned int u = __float_as_uint(f);
    u += 0x7fffu + ((u >> 16) & 1u);      // round-to-nearest-even
    return (unsigned short)(u >> 16);
}

// exp2-form nonlinearities (log2e pre-folded into the operand by caller)
__device__ __forceinline__ float sig_e2(float ylog2e) {       // sigma(x), y = x*log2e
    return __builtin_amdgcn_rcpf(1.0f + __builtin_amdgcn_exp2f(-ylog2e));
}
__device__ __forceinline__ float tanh_e2(float y2log2e) {     // tanh(x), y = 2x*log2e
    return __builtin_fmaf(-2.0f,
        __builtin_amdgcn_rcpf(1.0f + __builtin_amdgcn_exp2f(y2log2e)), 1.0f);
}

// Per-output-unit scales: one wave per row j of w_hh.
__global__ void pack_scales(const float* __restrict__ whh, float* __restrict__ scales) {
    int wid  = blockIdx.x * 4 + (threadIdx.x >> 6);   // 0..767
    int lane = threadIdx.x & 63;
    const float* src = whh + (size_t)wid * 256 + lane * 4;
    float m = 0.0f;
#pragma unroll
    for (int j = 0; j < 4; ++j) m = fmaxf(m, fabsf(src[j]));
#pragma unroll
    for (int d = 1; d < 64; d <<= 1) m = fmaxf(m, __shfl_xor(m, d, 64));
    if (lane == 0) scales[wid] = m;
}

// Pack w_hh [768,256] fp32 -> i8 16x16x64 B-frags (r13-verified layout).
__global__ void pack_whh_i8(const float* __restrict__ whh, const float* __restrict__ scales,
                            signed char* __restrict__ dst) {
    int tid  = blockIdx.x * blockDim.x + threadIdx.x;  // 12288 threads
    int lane = tid & 63;
    int frag = tid >> 6;                               // 0..191
    int kc   = frag & 3;
    int sub  = (frag >> 2) % 6;
    int w    = frag / 24;
    int g = sub >> 1, cs = sub & 1;
    int col  = w * 32 + cs * 16 + (lane & 15);
    int jout = g * 256 + col;
    int k0   = kc * 64 + ((lane >> 4) << 4);
    const float* src = whh + (size_t)jout * 256 + k0;
    float inv = 127.0f / scales[jout];
    signed char q[16];
#pragma unroll
    for (int j = 0; j < 16; ++j) {
        float v = __builtin_rintf(src[j] * inv);
        v = fminf(fmaxf(v, -127.0f), 127.0f);
        q[j] = (signed char)(int)v;
    }
    *(intx4*)(dst + (size_t)frag * 1024 + lane * 16) = *(intx4*)q;
}

// Pack fc_w [256,128] fp32 -> bf16 16x16x32 B-frags (r9 layout).
__global__ void pack_fcw(const float* __restrict__ fcw, unsigned short* __restrict__ dst) {
    int tid  = blockIdx.x * blockDim.x + threadIdx.x;  // 4096 threads
    int lane = tid & 63;
    int frag = tid >> 6;                               // 0..63
    int kc   = frag & 3;
    int cs   = (frag >> 2) & 1;
    int w    = frag >> 3;
    int col  = w * 32 + cs * 16 + (lane & 15);
    int k0   = kc * 32 + ((lane >> 4) << 3);
    const float* src = fcw + col * 128 + k0;
    unsigned int u[4];
#pragma unroll
    for (int j = 0; j < 4; ++j)
        u[j] = (unsigned int)f2bf(src[2 * j]) | ((unsigned int)f2bf(src[2 * j + 1]) << 16);
    *(uint4*)(dst + frag * 512 + lane * 8) = make_uint4(u[0], u[1], u[2], u[3]);
}

// Quantize out_w [2,256] -> i8 proj B-frags [slice4][lane][16B] + row scales.
__global__ void pack_outw_i8(const float* __restrict__ out_w,
                             signed char* __restrict__ dst, float* __restrict__ swout) {
    __shared__ float sw[2];
    int tid = threadIdx.x;
    if (tid < 128) {
        int o = tid >> 6, lane = tid & 63;
        const float* src = out_w + o * 256 + lane * 4;
        float m = 0.0f;
#pragma unroll
        for (int j = 0; j < 4; ++j) m = fmaxf(m, fabsf(src[j]));
#pragma unroll
        for (int d = 1; d < 64; d <<= 1) m = fmaxf(m, __shfl_xor(m, d, 64));
        if (lane == 0) { sw[o] = m; swout[o] = m; }
    }
    __syncthreads();
    int sl = tid >> 6, lane = tid & 63;
    int n  = lane & 15;
    int k0 = sl * 64 + ((lane >> 4) << 4);
    signed char q[16];
#pragma unroll
    for (int j = 0; j < 16; ++j) {
        float v = 0.0f;
        if (n < 2) {
            v = __builtin_rintf(out_w[n * 256 + k0 + j] * (127.0f / sw[n]));
            v = fminf(fmaxf(v, -127.0f), 127.0f);
        }
        q[j] = (signed char)(int)v;
    }
    *(intx4*)(dst + sl * 1024 + lane * 16) = *(intx4*)q;
}

// Persistent GRU r19: 256 blocks x 1024 threads (16 waves), 32 rows/block,
// wave owns 16 cols -> ALL 3 gates' i8 frags in regs (12 frags = 48 VGPR),
// NO weight LDS (r18's 64 KB duplicated wlds deleted; LDS = 19.5 KB).
// Total regs ~116 <= 128 -> 4 waves/SIMD resident, single pass (r18 ran 2
// sequential passes at 2 waves/SIMD: occupancy 23.5%). More waves/SIMD fills
// dependency gaps inside each phase; barrier count unchanged (1/step).
// i8 everywhere (r14); exp2-form gates (r15+).
__global__ __launch_bounds__(1024, 4) void gru_main(
    const float* __restrict__ z,
    const float* __restrict__ fc_b,
    const float* __restrict__ b_ih,
    const float* __restrict__ b_hh,
    const float* __restrict__ out_b,
    const unsigned char* __restrict__ ws,
    float* __restrict__ out)
{
    extern __shared__ unsigned char smem[];
    signed char* h8a  = (signed char*)smem;                 // buf0: 32 x 272
    signed char* h8b  = (signed char*)(smem + H8B_OFF);     // buf1
    float*       obuf = (float*)(smem + OBUF_OFF);          // [2][2][4][16][2]

    const int tid  = threadIdx.x;
    const int lane = tid & 63;
    const int wv   = tid >> 6;       // 0..15
    const int cg   = wv;             // 16-col group owned by this wave
    const int l15  = lane & 15;
    const int qd   = lane >> 4;
    const int rh   = (wv >> 2) & 1;  // proj row-half (waves 0-7)
    const int sl   = wv & 3;         // proj 64-col k-slice
    const int rb   = blockIdx.x * 32;

    // ---- ALL 3 gates' i8 weight frags into registers (12 frags = 48 VGPRs) ----
    // pack frag index: ((cg>>1)*6 + g*2 + (cg&1))*4 + kc
    intx4 wq[12];
#pragma unroll
    for (int g = 0; g < 3; ++g)
#pragma unroll
        for (int kc = 0; kc < 4; ++kc)
            wq[g * 4 + kc] = *(const intx4*)(ws + WQ_OFF
                + (size_t)((((cg >> 1) * 6 + g * 2 + (cg & 1)) * 4 + kc)) * 1024 + lane * 16);

    // ---- proj B-frag (i8; meaningful on waves 0-7) + per-lane constants ----
    intx4 bproj = *(const intx4*)(ws + OUTW_OFF + sl * 1024 + lane * 16);
    const float* swout = (const float*)(ws + SWOUT_OFF);
    float psc = (l15 < 2) ? swout[l15] * (1.0f / 16129.0f) : 0.0f;

    const float* scales = (const float*)(ws + SCW_OFF);
    float cbrE, cbzE, bhnE2, binE2, fcbE2, scqrE, scqzE, scqnE2;
    {
        int col = cg * 16 + l15;
        cbrE  = (b_ih[col]       + b_hh[col])       * LOG2E;
        cbzE  = (b_ih[256 + col] + b_hh[256 + col]) * LOG2E;
        binE2 = b_ih[512 + col] * (2.0f * LOG2E);
        bhnE2 = b_hh[512 + col] * (2.0f * LOG2E);
        fcbE2 = fc_b[col] * (2.0f * LOG2E);
        scqrE  = scales[col]       * (LOG2E / 16129.0f);
        scqzE  = scales[256 + col] * (LOG2E / 16129.0f);
        scqnE2 = scales[512 + col] * (2.0f * LOG2E / 16129.0f);
    }
    float ob = out_b[tid & 1];

    // ---- h0 = tanh(z @ fc_w^T + fc_b): bf16 MFMA, A-frags direct from global ----
    floatx4 a0f[2];
#pragma unroll
    for (int rt = 0; rt < 2; ++rt) a0f[rt] = (floatx4){0.f, 0.f, 0.f, 0.f};
#pragma unroll
    for (int kc = 0; kc < 4; ++kc) {
        short8 bfr = *(const short8*)(ws + FCW_OFF + (size_t)(cg * 4 + kc) * 1024 + lane * 16);
#pragma unroll
        for (int rt = 0; rt < 2; ++rt) {
            const float* zp = z + (size_t)(rb + rt * 16 + l15) * LATENT + kc * 32 + qd * 8;
            short8 afr;
#pragma unroll
            for (int j = 0; j < 8; ++j) afr[j] = (short)f2bf(zp[j]);
            a0f[rt] = __builtin_amdgcn_mfma_f32_16x16x32_bf16(afr, bfr, a0f[rt], 0, 0, 0);
        }
    }

    float hm[2][4];
#pragma unroll
    for (int rt = 0; rt < 2; ++rt)
#pragma unroll
        for (int r = 0; r < 4; ++r) {
            float h = tanh_e2(__builtin_fmaf(a0f[rt][r], 2.0f * LOG2E, fcbE2));
            hm[rt][r] = h;
            h8a[(rt * 16 + qd * 4 + r) * H8_STRIDE + cg * 16 + l15] =
                (signed char)(int)__builtin_rintf(h * 127.0f);
        }
    __syncthreads();

    // ---- 180 monolithic steps, ONE barrier each ----
#pragma unroll 1
    for (int t = 0; t < T_SEQ; ++t) {
        const int p = t & 1;
        signed char* h8p = p ? h8b : h8a;       // read: state s_t
        signed char* h8n = p ? h8a : h8b;       // write: state s_{t+1}

        // gate MFMAs: 24 i8 (2 rt x 3 g x 4 kc); all B operands from regs
        intx4 acc[6];                            // [rt*3 + g]
#pragma unroll
        for (int s = 0; s < 6; ++s) acc[s] = (intx4){0, 0, 0, 0};
#pragma unroll
        for (int kc = 0; kc < 4; ++kc) {
            intx4 a80 = *(const intx4*)&h8p[(0  + l15) * H8_STRIDE + kc * 64 + qd * 16];
            intx4 a81 = *(const intx4*)&h8p[(16 + l15) * H8_STRIDE + kc * 64 + qd * 16];
#pragma unroll
            for (int g = 0; g < 3; ++g) {
                acc[g]     = __builtin_amdgcn_mfma_i32_16x16x64_i8(a80, wq[g * 4 + kc], acc[g],     0, 0, 0);
                acc[3 + g] = __builtin_amdgcn_mfma_i32_16x16x64_i8(a81, wq[g * 4 + kc], acc[3 + g], 0, 0, 0);
            }
        }

        // proj of s_t (out idx t-1): waves 0-7 = (row-half, 64-col slice)
        intx4 pj = (intx4){0, 0, 0, 0};
        if (wv < 8) {
            intx4 a8p = *(const intx4*)&h8p[(rh * 16 + l15) * H8_STRIDE + sl * 64 + qd * 16];
            pj = __builtin_amdgcn_mfma_i32_16x16x64_i8(a8p, bproj, pj, 0, 0, 0);
        }

        // flush obuf written at step t-1 (out idx t-2); wave 8 owns this
        if (t >= 2 && tid >= 512 && tid < 576) {
            int rl = (tid - 512) >> 1, o = tid & 1;
            int base = ((p ^ 1) * 2 + (rl >> 4)) * 128 + (rl & 15) * 2 + o;
            float s = ob + obuf[base] + obuf[base + 32] + obuf[base + 64] + obuf[base + 96];
            out[(size_t)(rb + rl) * (T_SEQ * 2) + (t - 2) * 2 + o] = s;
        }

        // gates -> s_{t+1} (exp2-form), write h8 next buffer
#pragma unroll
        for (int rt = 0; rt < 2; ++rt)
#pragma unroll
            for (int r = 0; r < 4; ++r) {
                float yr  = __builtin_fmaf((float)acc[rt * 3 + 0][r], scqrE,  cbrE);
                float yz  = __builtin_fmaf((float)acc[rt * 3 + 1][r], scqzE,  cbzE);
                float xn2 = __builtin_fmaf((float)acc[rt * 3 + 2][r], scqnE2, bhnE2);
                float gr = sig_e2(yr);
                float gz = sig_e2(yz);
                float gn = tanh_e2(__builtin_fmaf(gr, xn2, binE2));
                float h  = __builtin_fmaf(gz, hm[rt][r] - gn, gn);
                hm[rt][r] = h;
                h8n[(rt * 16 + qd * 4 + r) * H8_STRIDE + cg * 16 + l15] =
                    (signed char)(int)__builtin_rintf(h * 127.0f);
            }

        // stash proj partials (out idx t-1) into obuf[p]
        if (t >= 1 && wv < 8 && l15 < 2) {
#pragma unroll
            for (int r = 0; r < 4; ++r)
                obuf[(p * 2 + rh) * 128 + sl * 32 + (qd * 4 + r) * 2 + l15] = (float)pj[r] * psc;
        }

        __syncthreads();   // the single per-step barrier
    }

    // ---- epilogue ----
    if (tid < 64) {        // flush obuf[1] (stashed at t=179): out idx 178
        int rl = tid >> 1, o = tid & 1;
        int base = (1 * 2 + (rl >> 4)) * 128 + (rl & 15) * 2 + o;
        float s = ob + obuf[base] + obuf[base + 32] + obuf[base + 64] + obuf[base + 96];
        out[(size_t)(rb + rl) * (T_SEQ * 2) + 178 * 2 + o] = s;
    }
    if (wv < 8) {          // proj of s_180 (in h8a after step 179) -> obuf[0]
        intx4 a8p = *(const intx4*)&h8a[(rh * 16 + l15) * H8_STRIDE + sl * 64 + qd * 16];
        intx4 pj = (intx4){0, 0, 0, 0};
        pj = __builtin_amdgcn_mfma_i32_16x16x64_i8(a8p, bproj, pj, 0, 0, 0);
        if (l15 < 2)
#pragma unroll
            for (int r = 0; r < 4; ++r)
                obuf[(0 * 2 + rh) * 128 + sl * 32 + (qd * 4 + r) * 2 + l15] = (float)pj[r] * psc;
    }
    __syncthreads();
    if (tid < 64) {        // flush obuf[0]: out idx 179
        int rl = tid >> 1, o = tid & 1;
        int base = (0 * 2 + (rl >> 4)) * 128 + (rl & 15) * 2 + o;
        float s = ob + obuf[base] + obuf[base + 32] + obuf[base + 64] + obuf[base + 96];
        out[(size_t)(rb + rl) * (T_SEQ * 2) + 179 * 2 + o] = s;
    }
}

extern "C" void kernel_launch(void* const* d_in, const int* in_sizes, int n_in,
                              void* d_out, int out_size, void* d_ws, size_t ws_size,
                              hipStream_t stream) {
    const float* z     = (const float*)d_in[0];
    const float* fc_w  = (const float*)d_in[1];
    const float* fc_b  = (const float*)d_in[2];
    // d_in[3] = w_ih : unused (GRU input is all-zeros, gi = b_ih)
    const float* b_ih  = (const float*)d_in[4];
    const float* w_hh  = (const float*)d_in[5];
    const float* b_hh  = (const float*)d_in[6];
    const float* out_w = (const float*)d_in[7];
    const float* out_b = (const float*)d_in[8];
    float* out = (float*)d_out;
    unsigned char* ws = (unsigned char*)d_ws;   // needs 269,320 B

    hipFuncSetAttribute((const void*)gru_main,
                        hipFuncAttributeMaxDynamicSharedMemorySize, SMEM_BYTES);

    pack_scales<<<192, 256, 0, stream>>>(w_hh, (float*)(ws + SCW_OFF));
    pack_whh_i8<<<48, 256, 0, stream>>>(w_hh, (const float*)(ws + SCW_OFF),
                                        (signed char*)(ws + WQ_OFF));
    pack_fcw<<<16, 256, 0, stream>>>(fc_w, (unsigned short*)(ws + FCW_OFF));
    pack_outw_i8<<<1, 256, 0, stream>>>(out_w, (signed char*)(ws + OUTW_OFF),
                                        (float*)(ws + SWOUT_OFF));
    gru_main<<<256, 1024, SMEM_BYTES, stream>>>(z, fc_b, b_ih, b_hh, out_b, ws, out);
}